// Round 9
// baseline (191.996 us; speedup 1.0000x reference)
//
#include <hip/hip_runtime.h>
#include <hip/hip_bf16.h>
#include <math.h>

// Problem constants (B=8, C=128, H=W=64, G=2, gc=64, nH=4, dh=32, Hk=Wk=16, n=256)
#define HW 4096
#define NCH 128

typedef __attribute__((ext_vector_type(8))) short short8;
typedef __attribute__((ext_vector_type(4))) float f32x4;

__device__ __forceinline__ short f2bf(float f) {
  union { __hip_bfloat16 h; short s; } u;
  u.h = __float2bfloat16(f);
  return u.s;
}
__device__ __forceinline__ float bf2f(short s) {
  union { unsigned u; float f; } u;
  u.u = ((unsigned)(unsigned short)s) << 16;
  return u.f;
}

// ---------------------------------------------------------------------------
// K1: fused transpose + q-conv (wq converted inline from fp32, L2-hot).
//  phase 1: stage x tile (128c x 64m) in LDS
//  phase 2: write xT[b][m][c] bf16 (hi only; feeds sampling -> bf16 xs anyway)
//  phase 3: q MFMA bf16x3 split -> qT[b][m][o] fp32 (pos path needs fp32)
// ---------------------------------------------------------------------------
__global__ __launch_bounds__(256) void xq_kernel(
    const float* __restrict__ x, const float* __restrict__ wq,
    short* __restrict__ xT, float* __restrict__ qT) {
  __shared__ float s[128][65];  // 33.3 KB
  int tid = threadIdx.x;
  int b = blockIdx.y;
  int m0 = blockIdx.x * 64;
  {
    int ml = tid & 63, ch = tid >> 6;
#pragma unroll
    for (int i = 0; i < 32; ++i) {
      int c = i * 4 + ch;
      s[c][ml] = x[((size_t)(b * NCH + c)) * HW + m0 + ml];
    }
  }
  __syncthreads();
  // phase 2: bf16 transpose write, coalesced along c
  {
    int c = tid & 127, mh = tid >> 7;
#pragma unroll
    for (int i = 0; i < 32; ++i) {
      int m = i * 2 + mh;
      xT[((size_t)(b * HW + m0 + m)) * NCH + c] = f2bf(s[c][m]);
    }
  }
  // phase 3: q MFMA (weights converted inline)
  int w = tid >> 6, lane = tid & 63, l15 = lane & 15, qd = lane >> 4;
  int mrow = w * 16 + l15;
  f32x4 acc[8];
#pragma unroll
  for (int ot = 0; ot < 8; ++ot) acc[ot] = (f32x4){0.f, 0.f, 0.f, 0.f};
#pragma unroll
  for (int kc = 0; kc < 4; ++kc) {
    short8 ah, al;
#pragma unroll
    for (int j = 0; j < 8; ++j) {
      float v = s[kc * 32 + qd * 8 + j][mrow];
      short hi = f2bf(v);
      ah[j] = hi;
      al[j] = f2bf(v - bf2f(hi));
    }
#pragma unroll
    for (int ot = 0; ot < 8; ++ot) {
      const float* wr = wq + (size_t)(ot * 16 + l15) * NCH + kc * 32 + qd * 8;
      f32x4 w0 = *(const f32x4*)wr;
      f32x4 w1 = *(const f32x4*)(wr + 4);
      short8 bh, bl;
#pragma unroll
      for (int j = 0; j < 4; ++j) {
        short h0 = f2bf(w0[j]);
        bh[j] = h0;
        bl[j] = f2bf(w0[j] - bf2f(h0));
        short h1 = f2bf(w1[j]);
        bh[4 + j] = h1;
        bl[4 + j] = f2bf(w1[j] - bf2f(h1));
      }
      acc[ot] = __builtin_amdgcn_mfma_f32_16x16x32_bf16(ah, bh, acc[ot], 0, 0, 0);
      acc[ot] = __builtin_amdgcn_mfma_f32_16x16x32_bf16(al, bh, acc[ot], 0, 0, 0);
      acc[ot] = __builtin_amdgcn_mfma_f32_16x16x32_bf16(ah, bl, acc[ot], 0, 0, 0);
    }
  }
#pragma unroll
  for (int ot = 0; ot < 8; ++ot)
#pragma unroll
    for (int r = 0; r < 4; ++r)
      qT[((size_t)(b * HW + m0 + w * 16 + qd * 4 + r)) * NCH + ot * 16 + l15] =
          acc[ot][r];
}

// ---------------------------------------------------------------------------
// K2: conv_offset (1024 main blocks, one p per wave) + prep side blocks:
//  bx < 64           : main — depthwise 5x5 -> LN -> GELU -> 1x1(3) -> pos/dm
//  bx >= 64, id < 64 : wk/wv/wo -> bf16
//  bx >= 64, id >= 64: vertical-pair f16 RPE table (128x128 uint per head):
//     tab[h][row][col] = pack(v[row-1][col], v[row][col]), col 127 = zero
//     (cols x=-1 and x=127 of the sample domain are all-zero -> share col 127)
// ---------------------------------------------------------------------------
__device__ __forceinline__ float wsum64(float v) {
#pragma unroll
  for (int o = 32; o > 0; o >>= 1) v += __shfl_xor(v, o);
  return v;
}

__global__ __launch_bounds__(256) void conv_offset_kernel(
    const float* __restrict__ qT, const float* __restrict__ w_dw,
    const float* __restrict__ ln_w, const float* __restrict__ w_off,
    const float* __restrict__ wk, const float* __restrict__ wv,
    const float* __restrict__ wo, const float* __restrict__ rpe,
    float* __restrict__ pos, float* __restrict__ dm,
    short* __restrict__ wk_bf, short* __restrict__ wv_bf,
    short* __restrict__ wo_bf, unsigned* __restrict__ tab) {
  int tid = threadIdx.x;
  if (blockIdx.x >= 64) {
    int id = (blockIdx.x - 64) * 16 + blockIdx.y;  // 0..319
    if (id < 64) {
      int i = id * 256 + tid;
      wk_bf[i] = f2bf(wk[i]);
      wv_bf[i] = f2bf(wv[i]);
      wo_bf[i] = f2bf(wo[i]);
    } else {
      int i = (id - 64) * 256 + tid;  // 0..65535
      int h = i >> 14, r = i & 16383;
      int row = r >> 7, col = r & 127;
      float lo = 0.f, hi = 0.f;
      if (col < 127) {
        if (row >= 1) lo = rpe[h * 16129 + (row - 1) * 127 + col];
        if (row < 127) hi = rpe[h * 16129 + row * 127 + col];
      }
      union { unsigned u; _Float16 h2[2]; } pk;
      pk.h2[0] = (_Float16)lo;
      pk.h2[1] = (_Float16)hi;
      tab[i] = pk.u;
    }
    return;
  }
  int c = tid & 63;
  int p = blockIdx.x * 4 + (tid >> 6);
  int bg = blockIdx.y;
  int py = p >> 4, px = p & 15;
  const float* qp = qT + (size_t)(bg >> 1) * HW * NCH + (bg & 1) * 64 + c;
  const float* wd = w_dw + c * 25;
  float acc = 0.f;
#pragma unroll
  for (int ky = 0; ky < 5; ++ky) {
    int iy = 4 * py + ky - 2;
    if (iy < 0 || iy >= 64) continue;
#pragma unroll
    for (int kx = 0; kx < 5; ++kx) {
      int ix = 4 * px + kx - 2;
      if (ix < 0 || ix >= 64) continue;
      acc += wd[ky * 5 + kx] * qp[(size_t)(iy * 64 + ix) * NCH];
    }
  }
  float mean = wsum64(acc) * (1.f / 64.f);
  float msq = wsum64(acc * acc) * (1.f / 64.f);
  float var = msq - mean * mean;  // jnp.var (ddof=0)
  float g = acc * rsqrtf(var + 1e-5f) * ln_w[c];
  g = 0.5f * g * (1.f + erff(g * 0.70710678118654752f));  // exact GELU
  float o0 = wsum64(w_off[c] * g);
  float o1 = wsum64(w_off[64 + c] * g);
  float o2 = wsum64(w_off[128 + c] * g);
  if (c == 0) {
    int idx = bg * 256 + p;
    pos[idx * 2] = tanhf(o0) * (1.f / 16.f) + ((py + 0.5f) * (1.f / 8.f) - 1.f);
    pos[idx * 2 + 1] = tanhf(o1) * (1.f / 16.f) + ((px + 0.5f) * (1.f / 8.f) - 1.f);
    dm[idx] = 1.f / (1.f + expf(-o2));
  }
}

// ---------------------------------------------------------------------------
// K3: xsT[b][n][c] bf16 = grid_sample(x, pos)*dm.  One wave per p; lanes over
// c; bf16 gathers (128B/corner coalesced).  1024 blocks.
// ---------------------------------------------------------------------------
__global__ __launch_bounds__(256) void sample_xs_kernel(
    const short* __restrict__ xT, const float* __restrict__ pos,
    const float* __restrict__ dm, short* __restrict__ xsT) {
  int tid = threadIdx.x;
  int c = tid & 63;
  int p = blockIdx.y * 4 + (tid >> 6);
  int bg = blockIdx.x;
  int b = bg >> 1, ch0 = (bg & 1) * 64;
  int idx = bg * 256 + p;
  float posy = pos[idx * 2], posx = pos[idx * 2 + 1];
  float dmv = dm[idx];
  float gx = (posx + 1.f) * 31.5f;
  float gy = (posy + 1.f) * 31.5f;
  float x0f = floorf(gx), y0f = floorf(gy);
  int ix = (int)x0f, iy = (int)y0f;
  float fx = gx - x0f, fy = gy - y0f;
  float w00 = (1.f - fx) * (1.f - fy), w10 = fx * (1.f - fy);
  float w01 = (1.f - fx) * fy, w11 = fx * fy;
  bool vx0 = (ix >= 0 && ix < 64), vx1 = (ix + 1 >= 0 && ix + 1 < 64);
  bool vy0 = (iy >= 0 && iy < 64), vy1 = (iy + 1 >= 0 && iy + 1 < 64);
  if (!(vx0 && vy0)) w00 = 0.f;
  if (!(vx1 && vy0)) w10 = 0.f;
  if (!(vx0 && vy1)) w01 = 0.f;
  if (!(vx1 && vy1)) w11 = 0.f;
  int x0c = min(max(ix, 0), 63), x1c = min(max(ix + 1, 0), 63);
  int y0c = min(max(iy, 0), 63), y1c = min(max(iy + 1, 0), 63);
  size_t rb = (size_t)b * HW * NCH + ch0 + c;
  float v = w00 * bf2f(xT[rb + (size_t)(y0c * 64 + x0c) * NCH]) +
            w10 * bf2f(xT[rb + (size_t)(y0c * 64 + x1c) * NCH]) +
            w01 * bf2f(xT[rb + (size_t)(y1c * 64 + x0c) * NCH]) +
            w11 * bf2f(xT[rb + (size_t)(y1c * 64 + x1c) * NCH]);
  xsT[((size_t)(b * 256 + p)) * NCH + ch0 + c] = f2bf(v * dmv);
}

// ---------------------------------------------------------------------------
// K4: k,v via MFMA from xsT.  kbf[bh][n][dh], vbf[bh][dh][n].
// ---------------------------------------------------------------------------
__global__ __launch_bounds__(256) void kv_mfma_kernel(
    const short* __restrict__ xsT, const short* __restrict__ wk_bf,
    const short* __restrict__ wv_bf, short* __restrict__ kbf,
    short* __restrict__ vbf) {
  int tid = threadIdx.x;
  int w = tid >> 6, lane = tid & 63, l15 = lane & 15, qd = lane >> 4;
  int bh = blockIdx.x, b = bh >> 2;
  int n0 = blockIdx.y * 64 + w * 16;
  f32x4 acc[2];
  acc[0] = (f32x4){0.f, 0.f, 0.f, 0.f};
  acc[1] = (f32x4){0.f, 0.f, 0.f, 0.f};

  size_t xrow = ((size_t)(b * 256 + n0 + l15)) * NCH + qd * 8;
  if (blockIdx.z == 0) {  // K
#pragma unroll
    for (int kc = 0; kc < 4; ++kc) {
      short8 a = *(const short8*)&xsT[xrow + kc * 32];
#pragma unroll
      for (int ot = 0; ot < 2; ++ot) {
        short8 bb = *(const short8*)&wk_bf[(size_t)((bh & 3) * 32 + ot * 16 + l15) * NCH + kc * 32 + qd * 8];
        acc[ot] = __builtin_amdgcn_mfma_f32_16x16x32_bf16(a, bb, acc[ot], 0, 0, 0);
      }
    }
#pragma unroll
    for (int ot = 0; ot < 2; ++ot)
#pragma unroll
      for (int r = 0; r < 4; ++r)
        kbf[((size_t)(bh * 256 + n0 + qd * 4 + r)) * 32 + ot * 16 + l15] =
            f2bf(acc[ot][r]);
  } else {  // V
#pragma unroll
    for (int kc = 0; kc < 4; ++kc) {
      short8 bb = *(const short8*)&xsT[xrow + kc * 32];
#pragma unroll
      for (int ot = 0; ot < 2; ++ot) {
        short8 a = *(const short8*)&wv_bf[(size_t)((bh & 3) * 32 + ot * 16 + l15) * NCH + kc * 32 + qd * 8];
        acc[ot] = __builtin_amdgcn_mfma_f32_16x16x32_bf16(a, bb, acc[ot], 0, 0, 0);
      }
    }
#pragma unroll
    for (int ot = 0; ot < 2; ++ot)
#pragma unroll
      for (int r = 0; r < 4; ++r)
        vbf[((size_t)(bh * 32 + ot * 16 + qd * 4 + r)) * 256 + n0 + l15] =
            f2bf(acc[ot][r]);
  }
}

// ---------------------------------------------------------------------------
// K5: MFMA attention.  The query row y = blockIdx.x is block-uniform, so gy
// spans only +/-33 table rows -> stage a 72-row window of the vertical-pair
// f16 table (72*128*4 = 36864 B -> 4 blocks/CU).  Bilinear = 2 aligned
// ds_read_b32, no masks.  pos from global (quad-uniform L1 broadcast).
// P (raw exp) overlays the window after barrier 2; norm folded into epilogue.
// ---------------------------------------------------------------------------
#define PROW 264    // bf16 elems per P row (528 B); P = 4*16*264*2 = 33792 B
#define TROWS 72    // staged table rows; window proven to cover y0+1 range

__global__ __launch_bounds__(256) void attn_kernel(
    const float* __restrict__ qT, const short* __restrict__ kbf,
    const short* __restrict__ vbf, const float* __restrict__ pos,
    const unsigned* __restrict__ tabg, short* __restrict__ outT) {
  __shared__ __align__(16) unsigned s_tab[TROWS * 128];  // 36864 B
  short* s_p = (short*)s_tab;

  int tid = threadIdx.x;
  int wv = tid >> 6;
  int lane = tid & 63;
  int l15 = lane & 15;
  int qd = lane >> 4;
  int bh = blockIdx.y;
  int b = bh >> 2, h = bh & 3;
  int bg = b * 2 + (h >> 1);
  int m0 = blockIdx.x * 64 + wv * 16;

  // block-uniform query row -> gy0 and the 72-row staging window
  float ry = ((float)blockIdx.x + 0.5f) * (1.f / 32.f) - 1.f;
  float gy0 = 63.f + ry * 31.5f;                  // in [32, 94]
  int row0 = min(max((int)floorf(gy0) - 34, 0), 128 - TROWS);

  // stage the window: TROWS*128 uints = 2304 uint4
  {
    const uint4* src = (const uint4*)(tabg + (size_t)h * 16384 + row0 * 128);
    uint4* dst = (uint4*)s_tab;
#pragma unroll
    for (int i = 0; i < 9; ++i) dst[i * 256 + tid] = src[i * 256 + tid];
  }

  short8 qfrag;
  {
    const float* qg = qT + ((size_t)(b * HW + m0 + l15)) * NCH + h * 32 + qd * 8;
    f32x4 a0 = *(const f32x4*)qg;
    f32x4 a1 = *(const f32x4*)(qg + 4);
#pragma unroll
    for (int j = 0; j < 4; ++j) {
      qfrag[j] = f2bf(a0[j]);
      qfrag[4 + j] = f2bf(a1[j]);
    }
  }

  f32x4 acc[16];
  {
    const short* kb = kbf + ((size_t)bh * 256 + l15) * 32 + qd * 8;
#pragma unroll
    for (int t = 0; t < 16; ++t) {
      short8 kf = *(const short8*)(kb + t * 16 * 32);
      acc[t] = __builtin_amdgcn_mfma_f32_16x16x32_bf16(
          kf, qfrag, (f32x4){0.f, 0.f, 0.f, 0.f}, 0, 0, 0);
    }
  }
  __syncthreads();  // window staged

  int m = m0 + l15;
  float gx0 = ((((float)(m & 63) + 0.5f) * (1.f / 32.f) - 1.f) * 0.5f + 1.f) * 63.f;
  float gyb = gy0 - (float)row0 + 1.f;  // fold row0 + the +1 row offset
  const float* posg = pos + (size_t)bg * 512;
  float mx = -1e30f;
#pragma unroll
  for (int t = 0; t < 16; ++t) {
    const f32x4* pp4 = (const f32x4*)&posg[(t * 16 + qd * 4) * 2];
    f32x4 pA = pp4[0];  // p0y p0x p1y p1x  (quad-uniform -> broadcast)
    f32x4 pB = pp4[1];  // p2y p2x p3y p3x
    float py[4] = {pA[0], pA[2], pB[0], pB[2]};
    float px[4] = {pA[1], pA[3], pB[1], pB[3]};
#pragma unroll
    for (int r = 0; r < 4; ++r) {
      float gy = gyb - py[r] * 31.5f;   // = (true gy) - row0 + 1, in [1, 71.99]
      float gx = gx0 - px[r] * 31.5f;
      float y0f = floorf(gy), x0f = floorf(gx);
      float fy = gy - y0f, fx = gx - x0f;
      int row = (int)y0f << 7;          // (y0+1-row0)*128, in window
      int xl = (int)x0f;                // in [-1,126]
      unsigned left = s_tab[row + (xl & 127)];   // x=-1 -> zero col 127
      unsigned right = s_tab[row + xl + 1];      // x+1=127 -> zero col 127
      union { unsigned u; _Float16 h2[2]; } L, R;
      L.u = left;
      R.u = right;
      float t00 = (float)L.h2[0], t01 = (float)L.h2[1];
      float t10 = (float)R.h2[0], t11 = (float)R.h2[1];
      float r0 = t00 + fx * (t10 - t00);
      float r1 = t01 + fx * (t11 - t01);
      float bias = r0 + fy * (r1 - r0);
      float s = fmaf(acc[t][r], 0.17677669529663688f, bias);
      acc[t][r] = s;
      mx = fmaxf(mx, s);
    }
  }
  mx = fmaxf(mx, __shfl_xor(mx, 16));
  float M = fmaxf(mx, __shfl_xor(mx, 32));

  float sm = 0.f;
#pragma unroll
  for (int t = 0; t < 16; ++t) {
#pragma unroll
    for (int r = 0; r < 4; ++r) {
      float e = __expf(acc[t][r] - M);
      acc[t][r] = e;
      sm += e;
    }
  }
  sm += __shfl_xor(sm, 16);
  sm += __shfl_xor(sm, 32);
  float inv = 1.f / sm;

  __syncthreads();  // all table reads done before P overlays

  // write raw exp P (bf16); normalization folded into the epilogue
  {
    short* pw = s_p + wv * 16 * PROW + l15 * PROW;
#pragma unroll
    for (int t = 0; t < 16; ++t) {
      int n = t * 16 + qd * 4;
      short4 pk;
      pk.x = f2bf(acc[t][0]);
      pk.y = f2bf(acc[t][1]);
      pk.z = f2bf(acc[t][2]);
      pk.w = f2bf(acc[t][3]);
      *(short4*)(pw + n) = pk;
    }
  }
  // no barrier: each wave reads only its own P region

  f32x4 o0 = {0.f, 0.f, 0.f, 0.f}, o1 = {0.f, 0.f, 0.f, 0.f};
  {
    const short* vb = vbf + ((size_t)bh * 32 + l15) * 256 + qd * 8;
    const short* pr = s_p + wv * 16 * PROW + l15 * PROW + qd * 8;
#pragma unroll
    for (int ch = 0; ch < 8; ++ch) {
      short8 pf = *(const short8*)(pr + ch * 32);
      short8 v0 = *(const short8*)(vb + ch * 32);
      short8 v1 = *(const short8*)(vb + 16 * 256 + ch * 32);
      o0 = __builtin_amdgcn_mfma_f32_16x16x32_bf16(v0, pf, o0, 0, 0, 0);
      o1 = __builtin_amdgcn_mfma_f32_16x16x32_bf16(v1, pf, o1, 0, 0, 0);
    }
  }
  {
    size_t row = (size_t)(b * HW + m0 + l15) * NCH + h * 32 + qd * 4;
    short4 s0, s1;
    s0.x = f2bf(o0[0] * inv); s0.y = f2bf(o0[1] * inv);
    s0.z = f2bf(o0[2] * inv); s0.w = f2bf(o0[3] * inv);
    s1.x = f2bf(o1[0] * inv); s1.y = f2bf(o1[1] * inv);
    s1.z = f2bf(o1[2] * inv); s1.w = f2bf(o1[3] * inv);
    *(short4*)&outT[row] = s0;
    *(short4*)&outT[row + 16] = s1;
  }
}

// ---------------------------------------------------------------------------
// K6: final conv via MFMA: out[b][o][m] = sum_c wo[o][c] * outT[b][m][c]
// ---------------------------------------------------------------------------
__global__ __launch_bounds__(256) void wo_mfma_kernel(
    const short* __restrict__ attnT, const short* __restrict__ wo_bf,
    float* __restrict__ out) {
  int tid = threadIdx.x;
  int wv = tid >> 6;
  int lane = tid & 63;
  int l15 = lane & 15;
  int qd = lane >> 4;
  int b = blockIdx.x >> 6;
  int m0 = (blockIdx.x & 63) * 64 + wv * 16;

  f32x4 acc[8];
#pragma unroll
  for (int ot = 0; ot < 8; ++ot) acc[ot] = (f32x4){0.f, 0.f, 0.f, 0.f};

  const short* arow = attnT + (size_t)(b * HW + m0 + l15) * NCH + qd * 8;
  const short* wrow = wo_bf + (size_t)l15 * NCH + qd * 8;
#pragma unroll
  for (int kc = 0; kc < 4; ++kc) {
    short8 afrag = *(const short8*)(arow + kc * 32);
#pragma unroll
    for (int ot = 0; ot < 8; ++ot) {
      short8 bfrag = *(const short8*)(wrow + (size_t)ot * 16 * NCH + kc * 32);
      acc[ot] = __builtin_amdgcn_mfma_f32_16x16x32_bf16(afrag, bfrag, acc[ot],
                                                        0, 0, 0);
    }
  }
#pragma unroll
  for (int ot = 0; ot < 8; ++ot) {
    float* op = out + ((size_t)b * NCH + ot * 16 + l15) * HW + m0 + qd * 4;
    *(f32x4*)op = acc[ot];
  }
}

// ---------------------------------------------------------------------------
// launch  (6 kernels: xq, conv_offset(+prep), sample, kv, attn, wo)
// ---------------------------------------------------------------------------
extern "C" void kernel_launch(void* const* d_in, const int* in_sizes, int n_in,
                              void* d_out, int out_size, void* d_ws,
                              size_t ws_size, hipStream_t stream) {
  const float* x = (const float*)d_in[0];
  const float* w_dw = (const float*)d_in[1];
  const float* ln_w = (const float*)d_in[2];
  const float* w_off = (const float*)d_in[3];
  const float* wq = (const float*)d_in[4];
  const float* wk = (const float*)d_in[5];
  const float* wv = (const float*)d_in[6];
  const float* wo = (const float*)d_in[7];
  const float* rpe = (const float*)d_in[8];
  float* out = (float*)d_out;

  // qT lives in d_out (dead before wo_mfma writes out).
  // outT aliases xT (xT dead after sample_xs, before attn writes outT).
  float* qT = out;
  short* sb = (short*)d_ws;
  short* xT = sb;                       // 4194304 bf16 (8.4 MB) [alias: outT]
  short* outT = sb;
  short* xsT = sb + 4194304;            // 262144
  short* kbf = sb + 4456448;            // 262144
  short* vbf = sb + 4718592;            // 262144
  short* wk_bf = sb + 4980736;          // 16384
  short* wv_bf = sb + 4997120;          // 16384
  short* wo_bf = sb + 5013504;          // 16384
  unsigned* tab = (unsigned*)(sb + 5029888);  // 65536 uints (256 KB, 16B-al)
  float* pos = (float*)(sb + 5160960);  // 8192 fp32
  float* dm = pos + 8192;               // 4096 fp32
  // total ~10.4 MB

  xq_kernel<<<dim3(64, 8), 256, 0, stream>>>(x, wq, xT, qT);
  conv_offset_kernel<<<dim3(84, 16), 256, 0, stream>>>(
      qT, w_dw, ln_w, w_off, wk, wv, wo, rpe, pos, dm, wk_bf, wv_bf, wo_bf,
      tab);
  sample_xs_kernel<<<dim3(16, 64), 256, 0, stream>>>(xT, pos, dm, xsT);
  kv_mfma_kernel<<<dim3(32, 4, 2), 256, 0, stream>>>(xsT, wk_bf, wv_bf, kbf,
                                                     vbf);
  attn_kernel<<<dim3(64, 32), 256, 0, stream>>>(qT, kbf, vbf, pos, tab, outT);
  wo_mfma_kernel<<<512, 256, 0, stream>>>(outT, wo_bf, out);
}

// Round 10
// 182.185 us; speedup vs baseline: 1.0539x; 1.0539x over previous
//
#include <hip/hip_runtime.h>
#include <hip/hip_bf16.h>
#include <math.h>

// Problem constants (B=8, C=128, H=W=64, G=2, gc=64, nH=4, dh=32, Hk=Wk=16, n=256)
#define HW 4096
#define NCH 128

typedef __attribute__((ext_vector_type(8))) short short8;
typedef __attribute__((ext_vector_type(4))) float f32x4;

__device__ __forceinline__ short f2bf(float f) {
  union { __hip_bfloat16 h; short s; } u;
  u.h = __float2bfloat16(f);
  return u.s;
}
__device__ __forceinline__ float bf2f(short s) {
  union { unsigned u; float f; } u;
  u.u = ((unsigned)(unsigned short)s) << 16;
  return u.f;
}

// ---------------------------------------------------------------------------
// K1: fused transpose + q-conv (wq converted inline from fp32, L2-hot).
// ---------------------------------------------------------------------------
__global__ __launch_bounds__(256) void xq_kernel(
    const float* __restrict__ x, const float* __restrict__ wq,
    short* __restrict__ xT, float* __restrict__ qT) {
  __shared__ float s[128][65];  // 33.3 KB
  int tid = threadIdx.x;
  int b = blockIdx.y;
  int m0 = blockIdx.x * 64;
  {
    int ml = tid & 63, ch = tid >> 6;
#pragma unroll
    for (int i = 0; i < 32; ++i) {
      int c = i * 4 + ch;
      s[c][ml] = x[((size_t)(b * NCH + c)) * HW + m0 + ml];
    }
  }
  __syncthreads();
  // bf16 transpose write, coalesced along c
  {
    int c = tid & 127, mh = tid >> 7;
#pragma unroll
    for (int i = 0; i < 32; ++i) {
      int m = i * 2 + mh;
      xT[((size_t)(b * HW + m0 + m)) * NCH + c] = f2bf(s[c][m]);
    }
  }
  // q MFMA (weights converted inline)
  int w = tid >> 6, lane = tid & 63, l15 = lane & 15, qd = lane >> 4;
  int mrow = w * 16 + l15;
  f32x4 acc[8];
#pragma unroll
  for (int ot = 0; ot < 8; ++ot) acc[ot] = (f32x4){0.f, 0.f, 0.f, 0.f};
#pragma unroll
  for (int kc = 0; kc < 4; ++kc) {
    short8 ah, al;
#pragma unroll
    for (int j = 0; j < 8; ++j) {
      float v = s[kc * 32 + qd * 8 + j][mrow];
      short hi = f2bf(v);
      ah[j] = hi;
      al[j] = f2bf(v - bf2f(hi));
    }
#pragma unroll
    for (int ot = 0; ot < 8; ++ot) {
      const float* wr = wq + (size_t)(ot * 16 + l15) * NCH + kc * 32 + qd * 8;
      f32x4 w0 = *(const f32x4*)wr;
      f32x4 w1 = *(const f32x4*)(wr + 4);
      short8 bh, bl;
#pragma unroll
      for (int j = 0; j < 4; ++j) {
        short h0 = f2bf(w0[j]);
        bh[j] = h0;
        bl[j] = f2bf(w0[j] - bf2f(h0));
        short h1 = f2bf(w1[j]);
        bh[4 + j] = h1;
        bl[4 + j] = f2bf(w1[j] - bf2f(h1));
      }
      acc[ot] = __builtin_amdgcn_mfma_f32_16x16x32_bf16(ah, bh, acc[ot], 0, 0, 0);
      acc[ot] = __builtin_amdgcn_mfma_f32_16x16x32_bf16(al, bh, acc[ot], 0, 0, 0);
      acc[ot] = __builtin_amdgcn_mfma_f32_16x16x32_bf16(ah, bl, acc[ot], 0, 0, 0);
    }
  }
#pragma unroll
  for (int ot = 0; ot < 8; ++ot)
#pragma unroll
    for (int r = 0; r < 4; ++r)
      qT[((size_t)(b * HW + m0 + w * 16 + qd * 4 + r)) * NCH + ot * 16 + l15] =
          acc[ot][r];
}

// ---------------------------------------------------------------------------
// K2: conv_offset (1024 main blocks, one p per wave) + prep side blocks:
//  bx < 64           : main — depthwise 5x5 -> LN -> GELU -> 1x1(3) -> pos/dm
//  bx >= 64, id < 64 : wk/wv/wo -> bf16
//  bx >= 64, id >= 64: vertical-pair f16 RPE table (128x128 uint per head):
//     tab[h][row][col] = pack(v[row-1][col], v[row][col]), col 127 = zero
// ---------------------------------------------------------------------------
__device__ __forceinline__ float wsum64(float v) {
#pragma unroll
  for (int o = 32; o > 0; o >>= 1) v += __shfl_xor(v, o);
  return v;
}

__global__ __launch_bounds__(256) void conv_offset_kernel(
    const float* __restrict__ qT, const float* __restrict__ w_dw,
    const float* __restrict__ ln_w, const float* __restrict__ w_off,
    const float* __restrict__ wk, const float* __restrict__ wv,
    const float* __restrict__ wo, const float* __restrict__ rpe,
    float* __restrict__ pos, float* __restrict__ dm,
    short* __restrict__ wk_bf, short* __restrict__ wv_bf,
    short* __restrict__ wo_bf, unsigned* __restrict__ tab) {
  int tid = threadIdx.x;
  if (blockIdx.x >= 64) {
    int id = (blockIdx.x - 64) * 16 + blockIdx.y;  // 0..319
    if (id < 64) {
      int i = id * 256 + tid;
      wk_bf[i] = f2bf(wk[i]);
      wv_bf[i] = f2bf(wv[i]);
      wo_bf[i] = f2bf(wo[i]);
    } else {
      int i = (id - 64) * 256 + tid;  // 0..65535
      int h = i >> 14, r = i & 16383;
      int row = r >> 7, col = r & 127;
      float lo = 0.f, hi = 0.f;
      if (col < 127) {
        if (row >= 1) lo = rpe[h * 16129 + (row - 1) * 127 + col];
        if (row < 127) hi = rpe[h * 16129 + row * 127 + col];
      }
      union { unsigned u; _Float16 h2[2]; } pk;
      pk.h2[0] = (_Float16)lo;
      pk.h2[1] = (_Float16)hi;
      tab[i] = pk.u;
    }
    return;
  }
  int c = tid & 63;
  int p = blockIdx.x * 4 + (tid >> 6);
  int bg = blockIdx.y;
  int py = p >> 4, px = p & 15;
  const float* qp = qT + (size_t)(bg >> 1) * HW * NCH + (bg & 1) * 64 + c;
  const float* wd = w_dw + c * 25;
  float acc = 0.f;
#pragma unroll
  for (int ky = 0; ky < 5; ++ky) {
    int iy = 4 * py + ky - 2;
    if (iy < 0 || iy >= 64) continue;
#pragma unroll
    for (int kx = 0; kx < 5; ++kx) {
      int ix = 4 * px + kx - 2;
      if (ix < 0 || ix >= 64) continue;
      acc += wd[ky * 5 + kx] * qp[(size_t)(iy * 64 + ix) * NCH];
    }
  }
  float mean = wsum64(acc) * (1.f / 64.f);
  float msq = wsum64(acc * acc) * (1.f / 64.f);
  float var = msq - mean * mean;  // jnp.var (ddof=0)
  float g = acc * rsqrtf(var + 1e-5f) * ln_w[c];
  g = 0.5f * g * (1.f + erff(g * 0.70710678118654752f));  // exact GELU
  float o0 = wsum64(w_off[c] * g);
  float o1 = wsum64(w_off[64 + c] * g);
  float o2 = wsum64(w_off[128 + c] * g);
  if (c == 0) {
    int idx = bg * 256 + p;
    pos[idx * 2] = tanhf(o0) * (1.f / 16.f) + ((py + 0.5f) * (1.f / 8.f) - 1.f);
    pos[idx * 2 + 1] = tanhf(o1) * (1.f / 16.f) + ((px + 0.5f) * (1.f / 8.f) - 1.f);
    dm[idx] = 1.f / (1.f + expf(-o2));
  }
}

// ---------------------------------------------------------------------------
// K3: xsT[b][n][c] bf16 = grid_sample(x, pos)*dm.  One wave per p; lanes over
// c; bf16 gathers (128B/corner coalesced).
// ---------------------------------------------------------------------------
__global__ __launch_bounds__(256) void sample_xs_kernel(
    const short* __restrict__ xT, const float* __restrict__ pos,
    const float* __restrict__ dm, short* __restrict__ xsT) {
  int tid = threadIdx.x;
  int c = tid & 63;
  int p = blockIdx.y * 4 + (tid >> 6);
  int bg = blockIdx.x;
  int b = bg >> 1, ch0 = (bg & 1) * 64;
  int idx = bg * 256 + p;
  float posy = pos[idx * 2], posx = pos[idx * 2 + 1];
  float dmv = dm[idx];
  float gx = (posx + 1.f) * 31.5f;
  float gy = (posy + 1.f) * 31.5f;
  float x0f = floorf(gx), y0f = floorf(gy);
  int ix = (int)x0f, iy = (int)y0f;
  float fx = gx - x0f, fy = gy - y0f;
  float w00 = (1.f - fx) * (1.f - fy), w10 = fx * (1.f - fy);
  float w01 = (1.f - fx) * fy, w11 = fx * fy;
  bool vx0 = (ix >= 0 && ix < 64), vx1 = (ix + 1 >= 0 && ix + 1 < 64);
  bool vy0 = (iy >= 0 && iy < 64), vy1 = (iy + 1 >= 0 && iy + 1 < 64);
  if (!(vx0 && vy0)) w00 = 0.f;
  if (!(vx1 && vy0)) w10 = 0.f;
  if (!(vx0 && vy1)) w01 = 0.f;
  if (!(vx1 && vy1)) w11 = 0.f;
  int x0c = min(max(ix, 0), 63), x1c = min(max(ix + 1, 0), 63);
  int y0c = min(max(iy, 0), 63), y1c = min(max(iy + 1, 0), 63);
  size_t rb = (size_t)b * HW * NCH + ch0 + c;
  float v = w00 * bf2f(xT[rb + (size_t)(y0c * 64 + x0c) * NCH]) +
            w10 * bf2f(xT[rb + (size_t)(y0c * 64 + x1c) * NCH]) +
            w01 * bf2f(xT[rb + (size_t)(y1c * 64 + x0c) * NCH]) +
            w11 * bf2f(xT[rb + (size_t)(y1c * 64 + x1c) * NCH]);
  xsT[((size_t)(b * 256 + p)) * NCH + ch0 + c] = f2bf(v * dmv);
}

// ---------------------------------------------------------------------------
// K4: k,v via MFMA from xsT.  kbf[bh][n][dh], vbf[bh][dh][n].
// ---------------------------------------------------------------------------
__global__ __launch_bounds__(256) void kv_mfma_kernel(
    const short* __restrict__ xsT, const short* __restrict__ wk_bf,
    const short* __restrict__ wv_bf, short* __restrict__ kbf,
    short* __restrict__ vbf) {
  int tid = threadIdx.x;
  int w = tid >> 6, lane = tid & 63, l15 = lane & 15, qd = lane >> 4;
  int bh = blockIdx.x, b = bh >> 2;
  int n0 = blockIdx.y * 64 + w * 16;
  f32x4 acc[2];
  acc[0] = (f32x4){0.f, 0.f, 0.f, 0.f};
  acc[1] = (f32x4){0.f, 0.f, 0.f, 0.f};

  size_t xrow = ((size_t)(b * 256 + n0 + l15)) * NCH + qd * 8;
  if (blockIdx.z == 0) {  // K
#pragma unroll
    for (int kc = 0; kc < 4; ++kc) {
      short8 a = *(const short8*)&xsT[xrow + kc * 32];
#pragma unroll
      for (int ot = 0; ot < 2; ++ot) {
        short8 bb = *(const short8*)&wk_bf[(size_t)((bh & 3) * 32 + ot * 16 + l15) * NCH + kc * 32 + qd * 8];
        acc[ot] = __builtin_amdgcn_mfma_f32_16x16x32_bf16(a, bb, acc[ot], 0, 0, 0);
      }
    }
#pragma unroll
    for (int ot = 0; ot < 2; ++ot)
#pragma unroll
      for (int r = 0; r < 4; ++r)
        kbf[((size_t)(bh * 256 + n0 + qd * 4 + r)) * 32 + ot * 16 + l15] =
            f2bf(acc[ot][r]);
  } else {  // V
#pragma unroll
    for (int kc = 0; kc < 4; ++kc) {
      short8 bb = *(const short8*)&xsT[xrow + kc * 32];
#pragma unroll
      for (int ot = 0; ot < 2; ++ot) {
        short8 a = *(const short8*)&wv_bf[(size_t)((bh & 3) * 32 + ot * 16 + l15) * NCH + kc * 32 + qd * 8];
        acc[ot] = __builtin_amdgcn_mfma_f32_16x16x32_bf16(a, bb, acc[ot], 0, 0, 0);
      }
    }
#pragma unroll
    for (int ot = 0; ot < 2; ++ot)
#pragma unroll
      for (int r = 0; r < 4; ++r)
        vbf[((size_t)(bh * 32 + ot * 16 + qd * 4 + r)) * 256 + n0 + l15] =
            f2bf(acc[ot][r]);
  }
}

// ---------------------------------------------------------------------------
// K5: MFMA attention.  Windowed vertical-pair f16 table (72 rows, 36864 B)
// + pos staged in LDS (2048 B) = 38912 B -> 4 blocks/CU.  Bilinear = 2
// aligned ds_read_b32, no masks; pos = quad-uniform ds_read_b128 (broadcast,
// conflict-free).  P (raw exp) overlays the table after barrier 2.
// ---------------------------------------------------------------------------
#define PROW 264    // bf16 elems per P row (528 B); P = 4*16*264*2 = 33792 B
#define TROWS 72    // staged table rows; window proven to cover y0+1 range

__global__ __launch_bounds__(256) void attn_kernel(
    const float* __restrict__ qT, const short* __restrict__ kbf,
    const short* __restrict__ vbf, const float* __restrict__ pos,
    const unsigned* __restrict__ tabg, short* __restrict__ outT) {
  __shared__ __align__(16) unsigned s_tab[TROWS * 128];  // 36864 B
  __shared__ __align__(16) float s_pos[512];             // 2048 B
  short* s_p = (short*)s_tab;

  int tid = threadIdx.x;
  int wv = tid >> 6;
  int lane = tid & 63;
  int l15 = lane & 15;
  int qd = lane >> 4;
  int bh = blockIdx.y;
  int b = bh >> 2, h = bh & 3;
  int bg = b * 2 + (h >> 1);
  int m0 = blockIdx.x * 64 + wv * 16;

  // block-uniform query row -> gy0 and the 72-row staging window
  float ry = ((float)blockIdx.x + 0.5f) * (1.f / 32.f) - 1.f;
  float gy0 = 63.f + ry * 31.5f;                  // in [32, 94]
  int row0 = min(max((int)floorf(gy0) - 34, 0), 128 - TROWS);

  // stage the window (2304 uint4) + pos (512 floats)
  {
    const uint4* src = (const uint4*)(tabg + (size_t)h * 16384 + row0 * 128);
    uint4* dst = (uint4*)s_tab;
#pragma unroll
    for (int i = 0; i < 9; ++i) dst[i * 256 + tid] = src[i * 256 + tid];
    const float* posg = pos + (size_t)bg * 512;
    s_pos[tid] = posg[tid];
    s_pos[256 + tid] = posg[256 + tid];
  }

  short8 qfrag;
  {
    const float* qg = qT + ((size_t)(b * HW + m0 + l15)) * NCH + h * 32 + qd * 8;
    f32x4 a0 = *(const f32x4*)qg;
    f32x4 a1 = *(const f32x4*)(qg + 4);
#pragma unroll
    for (int j = 0; j < 4; ++j) {
      qfrag[j] = f2bf(a0[j]);
      qfrag[4 + j] = f2bf(a1[j]);
    }
  }

  f32x4 acc[16];
  {
    const short* kb = kbf + ((size_t)bh * 256 + l15) * 32 + qd * 8;
#pragma unroll
    for (int t = 0; t < 16; ++t) {
      short8 kf = *(const short8*)(kb + t * 16 * 32);
      acc[t] = __builtin_amdgcn_mfma_f32_16x16x32_bf16(
          kf, qfrag, (f32x4){0.f, 0.f, 0.f, 0.f}, 0, 0, 0);
    }
  }
  __syncthreads();  // staging done

  int m = m0 + l15;
  float gx0 = ((((float)(m & 63) + 0.5f) * (1.f / 32.f) - 1.f) * 0.5f + 1.f) * 63.f;
  float gyb = gy0 - (float)row0 + 1.f;  // fold row0 + the +1 row offset
  float mx = -1e30f;
#pragma unroll
  for (int t = 0; t < 16; ++t) {
    const f32x4* pp4 = (const f32x4*)&s_pos[(t * 16 + qd * 4) * 2];
    f32x4 pA = pp4[0];  // p0y p0x p1y p1x  (quad-uniform LDS broadcast)
    f32x4 pB = pp4[1];  // p2y p2x p3y p3x
    float py[4] = {pA[0], pA[2], pB[0], pB[2]};
    float px[4] = {pA[1], pA[3], pB[1], pB[3]};
#pragma unroll
    for (int r = 0; r < 4; ++r) {
      float gy = gyb - py[r] * 31.5f;   // in [1, 71.99] within window
      float gx = gx0 - px[r] * 31.5f;
      float y0f = floorf(gy), x0f = floorf(gx);
      float fy = gy - y0f, fx = gx - x0f;
      int row = (int)y0f << 7;          // (y0+1-row0)*128
      int xl = (int)x0f;                // in [-1,126]
      unsigned left = s_tab[row + (xl & 127)];   // x=-1 -> zero col 127
      unsigned right = s_tab[row + xl + 1];      // x+1=127 -> zero col 127
      union { unsigned u; _Float16 h2[2]; } L, R;
      L.u = left;
      R.u = right;
      float t00 = (float)L.h2[0], t01 = (float)L.h2[1];
      float t10 = (float)R.h2[0], t11 = (float)R.h2[1];
      float r0 = t00 + fx * (t10 - t00);
      float r1 = t01 + fx * (t11 - t01);
      float bias = r0 + fy * (r1 - r0);
      float s = fmaf(acc[t][r], 0.17677669529663688f, bias);
      acc[t][r] = s;
      mx = fmaxf(mx, s);
    }
  }
  mx = fmaxf(mx, __shfl_xor(mx, 16));
  float M = fmaxf(mx, __shfl_xor(mx, 32));

  float sm = 0.f;
#pragma unroll
  for (int t = 0; t < 16; ++t) {
#pragma unroll
    for (int r = 0; r < 4; ++r) {
      float e = __expf(acc[t][r] - M);
      acc[t][r] = e;
      sm += e;
    }
  }
  sm += __shfl_xor(sm, 16);
  sm += __shfl_xor(sm, 32);
  float inv = 1.f / sm;

  __syncthreads();  // all table reads done before P overlays

  // write raw exp P (bf16); normalization folded into the epilogue
  {
    short* pw = s_p + wv * 16 * PROW + l15 * PROW;
#pragma unroll
    for (int t = 0; t < 16; ++t) {
      int n = t * 16 + qd * 4;
      short4 pk;
      pk.x = f2bf(acc[t][0]);
      pk.y = f2bf(acc[t][1]);
      pk.z = f2bf(acc[t][2]);
      pk.w = f2bf(acc[t][3]);
      *(short4*)(pw + n) = pk;
    }
  }
  // no barrier: each wave reads only its own P region

  f32x4 o0 = {0.f, 0.f, 0.f, 0.f}, o1 = {0.f, 0.f, 0.f, 0.f};
  {
    const short* vb = vbf + ((size_t)bh * 32 + l15) * 256 + qd * 8;
    const short* pr = s_p + wv * 16 * PROW + l15 * PROW + qd * 8;
#pragma unroll
    for (int ch = 0; ch < 8; ++ch) {
      short8 pf = *(const short8*)(pr + ch * 32);
      short8 v0 = *(const short8*)(vb + ch * 32);
      short8 v1 = *(const short8*)(vb + 16 * 256 + ch * 32);
      o0 = __builtin_amdgcn_mfma_f32_16x16x32_bf16(v0, pf, o0, 0, 0, 0);
      o1 = __builtin_amdgcn_mfma_f32_16x16x32_bf16(v1, pf, o1, 0, 0, 0);
    }
  }
  {
    size_t row = (size_t)(b * HW + m0 + l15) * NCH + h * 32 + qd * 4;
    short4 s0, s1;
    s0.x = f2bf(o0[0] * inv); s0.y = f2bf(o0[1] * inv);
    s0.z = f2bf(o0[2] * inv); s0.w = f2bf(o0[3] * inv);
    s1.x = f2bf(o1[0] * inv); s1.y = f2bf(o1[1] * inv);
    s1.z = f2bf(o1[2] * inv); s1.w = f2bf(o1[3] * inv);
    *(short4*)&outT[row] = s0;
    *(short4*)&outT[row + 16] = s1;
  }
}

// ---------------------------------------------------------------------------
// K6: final conv via MFMA: out[b][o][m] = sum_c wo[o][c] * outT[b][m][c]
// ---------------------------------------------------------------------------
__global__ __launch_bounds__(256) void wo_mfma_kernel(
    const short* __restrict__ attnT, const short* __restrict__ wo_bf,
    float* __restrict__ out) {
  int tid = threadIdx.x;
  int wv = tid >> 6;
  int lane = tid & 63;
  int l15 = lane & 15;
  int qd = lane >> 4;
  int b = blockIdx.x >> 6;
  int m0 = (blockIdx.x & 63) * 64 + wv * 16;

  f32x4 acc[8];
#pragma unroll
  for (int ot = 0; ot < 8; ++ot) acc[ot] = (f32x4){0.f, 0.f, 0.f, 0.f};

  const short* arow = attnT + (size_t)(b * HW + m0 + l15) * NCH + qd * 8;
  const short* wrow = wo_bf + (size_t)l15 * NCH + qd * 8;
#pragma unroll
  for (int kc = 0; kc < 4; ++kc) {
    short8 afrag = *(const short8*)(arow + kc * 32);
#pragma unroll
    for (int ot = 0; ot < 8; ++ot) {
      short8 bfrag = *(const short8*)(wrow + (size_t)ot * 16 * NCH + kc * 32);
      acc[ot] = __builtin_amdgcn_mfma_f32_16x16x32_bf16(afrag, bfrag, acc[ot],
                                                        0, 0, 0);
    }
  }
#pragma unroll
  for (int ot = 0; ot < 8; ++ot) {
    float* op = out + ((size_t)b * NCH + ot * 16 + l15) * HW + m0 + qd * 4;
    *(f32x4*)op = acc[ot];
  }
}

// ---------------------------------------------------------------------------
// launch  (6 kernels: xq, conv_offset(+prep), sample, kv, attn, wo)
// ---------------------------------------------------------------------------
extern "C" void kernel_launch(void* const* d_in, const int* in_sizes, int n_in,
                              void* d_out, int out_size, void* d_ws,
                              size_t ws_size, hipStream_t stream) {
  const float* x = (const float*)d_in[0];
  const float* w_dw = (const float*)d_in[1];
  const float* ln_w = (const float*)d_in[2];
  const float* w_off = (const float*)d_in[3];
  const float* wq = (const float*)d_in[4];
  const float* wk = (const float*)d_in[5];
  const float* wv = (const float*)d_in[6];
  const float* wo = (const float*)d_in[7];
  const float* rpe = (const float*)d_in[8];
  float* out = (float*)d_out;

  // qT lives in d_out (dead before wo_mfma writes out).
  // outT aliases xT (xT dead after sample_xs, before attn writes outT).
  float* qT = out;
  short* sb = (short*)d_ws;
  short* xT = sb;                       // 4194304 bf16 (8.4 MB) [alias: outT]
  short* outT = sb;
  short* xsT = sb + 4194304;            // 262144
  short* kbf = sb + 4456448;            // 262144
  short* vbf = sb + 4718592;            // 262144
  short* wk_bf = sb + 4980736;          // 16384
  short* wv_bf = sb + 4997120;          // 16384
  short* wo_bf = sb + 5013504;          // 16384
  unsigned* tab = (unsigned*)(sb + 5029888);  // 65536 uints (256 KB, 16B-al)
  float* pos = (float*)(sb + 5160960);  // 8192 fp32
  float* dm = pos + 8192;               // 4096 fp32
  // total ~10.4 MB

  xq_kernel<<<dim3(64, 8), 256, 0, stream>>>(x, wq, xT, qT);
  conv_offset_kernel<<<dim3(84, 16), 256, 0, stream>>>(
      qT, w_dw, ln_w, w_off, wk, wv, wo, rpe, pos, dm, wk_bf, wv_bf, wo_bf,
      tab);
  sample_xs_kernel<<<dim3(16, 64), 256, 0, stream>>>(xT, pos, dm, xsT);
  kv_mfma_kernel<<<dim3(32, 4, 2), 256, 0, stream>>>(xsT, wk_bf, wv_bf, kbf,
                                                     vbf);
  attn_kernel<<<dim3(64, 32), 256, 0, stream>>>(qT, kbf, vbf, pos, tab, outT);
  wo_mfma_kernel<<<512, 256, 0, stream>>>(outT, wo_bf, out);
}